// Round 22
// baseline (106.972 us; speedup 1.0000x reference)
//
#include <hip/hip_runtime.h>

#define NN   50000
#define NE   200000
#define INC  16
#define HIDC 32
#define EDGED 8
#define OUTC 32
#define MLPH 128
#define NACT 32

#define NPART 196   // ceil(NN / 256)

typedef float floatx4 __attribute__((ext_vector_type(4)));

// ---- hist + slot in one pass: the atomic counter IS the histogram ----
__global__ __launch_bounds__(256) void hist_slot_kernel(const int* __restrict__ edst,
                                                        int* __restrict__ deg,
                                                        int* __restrict__ slot) {
    int e = blockIdx.x * blockDim.x + threadIdx.x;
    if (e < NE) slot[e] = atomicAdd(&deg[edst[e]], 1);
}

// ---- scan pass 1: per-block sums ----
__global__ __launch_bounds__(256) void partial_kernel(const int* __restrict__ deg,
                                                      int* __restrict__ partials) {
    __shared__ int sm[256];
    int t = threadIdx.x, i = blockIdx.x * 256 + t;
    sm[t] = (i < NN) ? deg[i] : 0;
    __syncthreads();
    #pragma unroll
    for (int off = 128; off > 0; off >>= 1) {
        if (t < off) sm[t] += sm[t + off];
        __syncthreads();
    }
    if (t == 0) partials[blockIdx.x] = sm[0];
}

// ---- scan pass 2 (merged): every block prefixes the 196 partials itself,
//      then block-local scan -> row_off ----
__global__ __launch_bounds__(256) void rowoff2_kernel(const int* __restrict__ deg,
                                                      const int* __restrict__ partials,
                                                      int* __restrict__ row_off) {
    __shared__ int sp[NPART];
    __shared__ int sm[256];
    int t = threadIdx.x, bid = blockIdx.x;
    if (t < NPART) sp[t] = partials[t];
    __syncthreads();
    int base = 0;
    for (int i = 0; i < bid; ++i) base += sp[i];   // uniform, scalar-unit cheap

    int i = bid * 256 + t;
    int d = (i < NN) ? deg[i] : 0;
    sm[t] = d;
    __syncthreads();
    for (int off = 1; off < 256; off <<= 1) {
        int v = (t >= off) ? sm[t - off] : 0;
        __syncthreads();
        sm[t] += v;
        __syncthreads();
    }
    int excl = sm[t] - d + base;
    if (i < NN) {
        row_off[i] = excl;
        if (i == NN - 1) row_off[NN] = excl + d;   // == NE
    }
}

// ---- edge kernel: 4 lanes per edge, 1 edge/thread (800K threads = 12
//      waves/SIMD of TLP — the 2-edge version had only 1.5 and was
//      latency-bound at 47us despite half the LDS traffic). ~35 live regs:
//      no spill risk. Lane l owns channels {4l..4l+3, 16+4l..16+4l+3};
//      quad covers complete 64-B sectors; non-temporal dst-sorted stores. ----
__global__ __launch_bounds__(256, 4) void edge_q1_kernel(
    const float* __restrict__ x,
    const int*   __restrict__ esrc,
    const int*   __restrict__ edst,
    const float* __restrict__ ea,
    const float* __restrict__ We,        // [8][512] original layout
    const float* __restrict__ be,        // [512]
    const int*   __restrict__ row_off,   // [NN+1]
    const int*   __restrict__ slot,      // [NE]
    float*       __restrict__ sorted_msg) // [NE][32] dst-sorted rows
{
    __shared__ float sWe2[4 * 1032];  // [l][(i*8+cc)*8 + d]
    __shared__ float sbe2[4 * 132];   // [l][i*8+cc]
    int t = threadIdx.x;
    for (int idx = t; idx < 4 * 1032; idx += 256) {
        int l = idx / 1032, r = idx - l * 1032;
        float v = 0.f;
        if (r < 1024) {
            int d = r & 7, icc = r >> 3;
            int i = icc >> 3, cc = icc & 7;
            int h = ((cc & 4) << 2) + l * 4 + (cc & 3);   // channel
            v = We[d * 512 + i * 32 + h];
        }
        sWe2[idx] = v;
    }
    for (int idx = t; idx < 4 * 132; idx += 256) {
        int l = idx / 132, r = idx - l * 132;
        float v = 0.f;
        if (r < 128) {
            int i = r >> 3, cc = r & 7;
            int h = ((cc & 4) << 2) + l * 4 + (cc & 3);
            v = be[i * 32 + h];
        }
        sbe2[idx] = v;
    }
    __syncthreads();

    int gid = blockIdx.x * 256 + t;
    int e = gid >> 2;
    int l = gid & 3;
    if (e >= NE) return;

    int src = esrc[e];
    int pos = row_off[edst[e]] + slot[e];

    float ea8[8];
    {
        const float4* p = reinterpret_cast<const float4*>(ea) + (size_t)e * 2;
        float4 a = p[0], b = p[1];
        ea8[0]=a.x; ea8[1]=a.y; ea8[2]=a.z; ea8[3]=a.w;
        ea8[4]=b.x; ea8[5]=b.y; ea8[6]=b.z; ea8[7]=b.w;
    }

    float m[8];
    #pragma unroll
    for (int c = 0; c < 8; ++c) m[c] = 0.f;

    const float* wl = sWe2 + l * 1032;
    const float* bl = sbe2 + l * 132;
    const float4* xp = reinterpret_cast<const float4*>(x) + (size_t)src * 4;

    for (int i4 = 0; i4 < 4; ++i4) {        // rolled: keeps live ranges small
        float4 xv = xp[i4];
        float xs[4] = {xv.x, xv.y, xv.z, xv.w};
        const float* wb4 = wl + i4 * 256;
        const float* bb4 = bl + i4 * 32;
        #pragma unroll
        for (int ii = 0; ii < 4; ++ii) {
            const float* wbase = wb4 + ii * 64;
            const float* bbase = bb4 + ii * 8;
            float xi = xs[ii];
            #pragma unroll
            for (int cc = 0; cc < 8; ++cc) {
                const float* wr = wbase + cc * 8;
                float w = bbase[cc];
                #pragma unroll
                for (int d = 0; d < 8; ++d)
                    w = fmaf(ea8[d], wr[d], w);
                w = fmaxf(w, 0.f);
                m[cc] = fmaf(xi, w, m[cc]);
            }
        }
    }

    // slots 0..3 -> float offset l*4; slots 4..7 -> 16+l*4 (second sector)
    floatx4* o = reinterpret_cast<floatx4*>(sorted_msg + (size_t)pos * 32 + l * 4);
    floatx4 v;
    v = (floatx4){m[0], m[1], m[2], m[3]}; __builtin_nontemporal_store(v, o);
    v = (floatx4){m[4], m[5], m[6], m[7]}; __builtin_nontemporal_store(v, o + 4);
}

// ---- fused node kernel: quad per NODE PAIR (2 nodes/thread), 64-thread
//      blocks (R21-proven: 1563 one-wave blocks, fine CU balance), (64,1)
//      full register budget. ----
__global__ __launch_bounds__(64, 1) void node_fused_kernel(
    const float* __restrict__ x,
    const float* __restrict__ sorted_msg,  // [NE][32] dst-sorted
    const int*   __restrict__ row_off,
    const float* __restrict__ Wroot,   // [16][32]
    const float* __restrict__ bconv,
    const float* __restrict__ gamma,
    const float* __restrict__ beta,
    const float* __restrict__ Wlin,    // [32][32]
    const float* __restrict__ blin,
    const float* __restrict__ Wq1,     // [32][128]
    const float* __restrict__ bq1,
    const float* __restrict__ Wq2,     // [128][32]
    const float* __restrict__ bq2,
    float* __restrict__ out)
{
    __shared__ float sw1[4 * 1032];    // [l][k*32+j], stagger 1032
    int t = threadIdx.x;
    for (int w = t; w < 4096; w += 64) {
        int k = w >> 7, m = w & 127, l = m >> 5, j = m & 31;
        sw1[l * 1032 + k * 32 + j] = Wq1[w];
    }
    __syncthreads();

    int gid = blockIdx.x * 64 + t;
    int p = gid >> 2;                  // node pair
    int l = gid & 3;
    if (p >= NN / 2) return;
    int n0 = p * 2, n1 = p * 2 + 1;
    int o1 = l * 4;        // first channel-slice float offset
    int o2 = 16 + l * 4;   // second

    // ===== Phase A: feat for both nodes =====
    float h0[8], h1[8];
    {
        float4 a = *reinterpret_cast<const float4*>(bconv + o1);
        float4 b = *reinterpret_cast<const float4*>(bconv + o2);
        h0[0]=a.x; h0[1]=a.y; h0[2]=a.z; h0[3]=a.w;
        h0[4]=b.x; h0[5]=b.y; h0[6]=b.z; h0[7]=b.w;
        #pragma unroll
        for (int c = 0; c < 8; ++c) h1[c] = h0[c];
    }

    int r0 = row_off[n0], r1 = row_off[n1], r2 = row_off[n1 + 1];
    for (int k = r0; k < r1; ++k) {
        const float* row = sorted_msg + (size_t)k * 32;
        float4 a = *reinterpret_cast<const float4*>(row + o1);
        float4 b = *reinterpret_cast<const float4*>(row + o2);
        h0[0]+=a.x; h0[1]+=a.y; h0[2]+=a.z; h0[3]+=a.w;
        h0[4]+=b.x; h0[5]+=b.y; h0[6]+=b.z; h0[7]+=b.w;
    }
    for (int k = r1; k < r2; ++k) {
        const float* row = sorted_msg + (size_t)k * 32;
        float4 a = *reinterpret_cast<const float4*>(row + o1);
        float4 b = *reinterpret_cast<const float4*>(row + o2);
        h1[0]+=a.x; h1[1]+=a.y; h1[2]+=a.z; h1[3]+=a.w;
        h1[4]+=b.x; h1[5]+=b.y; h1[6]+=b.z; h1[7]+=b.w;
    }

    {
        const float4* xa = reinterpret_cast<const float4*>(x) + (size_t)n0 * 4;
        const float4* xb = reinterpret_cast<const float4*>(x) + (size_t)n1 * 4;
        #pragma unroll
        for (int i4 = 0; i4 < 4; ++i4) {
            float4 xv0 = xa[i4], xv1 = xb[i4];
            float xs0[4] = {xv0.x, xv0.y, xv0.z, xv0.w};
            float xs1[4] = {xv1.x, xv1.y, xv1.z, xv1.w};
            #pragma unroll
            for (int ii = 0; ii < 4; ++ii) {
                const float* wr = Wroot + (i4 * 4 + ii) * HIDC;
                float4 a = *reinterpret_cast<const float4*>(wr + o1);
                float4 b = *reinterpret_cast<const float4*>(wr + o2);
                float xi0 = xs0[ii], xi1 = xs1[ii];
                h0[0]=fmaf(xi0,a.x,h0[0]); h0[1]=fmaf(xi0,a.y,h0[1]);
                h0[2]=fmaf(xi0,a.z,h0[2]); h0[3]=fmaf(xi0,a.w,h0[3]);
                h0[4]=fmaf(xi0,b.x,h0[4]); h0[5]=fmaf(xi0,b.y,h0[5]);
                h0[6]=fmaf(xi0,b.z,h0[6]); h0[7]=fmaf(xi0,b.w,h0[7]);
                h1[0]=fmaf(xi1,a.x,h1[0]); h1[1]=fmaf(xi1,a.y,h1[1]);
                h1[2]=fmaf(xi1,a.z,h1[2]); h1[3]=fmaf(xi1,a.w,h1[3]);
                h1[4]=fmaf(xi1,b.x,h1[4]); h1[5]=fmaf(xi1,b.y,h1[5]);
                h1[6]=fmaf(xi1,b.z,h1[6]); h1[7]=fmaf(xi1,b.w,h1[7]);
            }
        }
    }

    // LayerNorm both nodes (quad butterfly on scalars) + ReLU
    float s0 = ((h0[0]+h0[1])+(h0[2]+h0[3])) + ((h0[4]+h0[5])+(h0[6]+h0[7]));
    float s1 = ((h1[0]+h1[1])+(h1[2]+h1[3])) + ((h1[4]+h1[5])+(h1[6]+h1[7]));
    s0 += __shfl_xor(s0, 1); s0 += __shfl_xor(s0, 2);
    s1 += __shfl_xor(s1, 1); s1 += __shfl_xor(s1, 2);
    float mu0 = s0 * (1.f / HIDC), mu1 = s1 * (1.f / HIDC);
    float v0 = 0.f, v1 = 0.f;
    #pragma unroll
    for (int c = 0; c < 8; ++c) {
        float d0 = h0[c] - mu0; v0 = fmaf(d0, d0, v0);
        float d1 = h1[c] - mu1; v1 = fmaf(d1, d1, v1);
    }
    v0 += __shfl_xor(v0, 1); v0 += __shfl_xor(v0, 2);
    v1 += __shfl_xor(v1, 1); v1 += __shfl_xor(v1, 2);
    float rs0 = rsqrtf(v0 * (1.f / HIDC) + 1e-5f);
    float rs1 = rsqrtf(v1 * (1.f / HIDC) + 1e-5f);
    {
        float4 g0 = *reinterpret_cast<const float4*>(gamma + o1);
        float4 g1 = *reinterpret_cast<const float4*>(gamma + o2);
        float4 b0 = *reinterpret_cast<const float4*>(beta + o1);
        float4 b1 = *reinterpret_cast<const float4*>(beta + o2);
        float gs[8] = {g0.x,g0.y,g0.z,g0.w,g1.x,g1.y,g1.z,g1.w};
        float bs[8] = {b0.x,b0.y,b0.z,b0.w,b1.x,b1.y,b1.z,b1.w};
        #pragma unroll
        for (int c = 0; c < 8; ++c) {
            h0[c] = fmaxf(fmaf((h0[c] - mu0) * rs0, gs[c], bs[c]), 0.f);
            h1[c] = fmaxf(fmaf((h1[c] - mu1) * rs1, gs[c], bs[c]), 0.f);
        }
    }

    // feat slices (complete sums per lane)
    float fA[8], fB[8];
    {
        float4 a = *reinterpret_cast<const float4*>(blin + o1);
        float4 b = *reinterpret_cast<const float4*>(blin + o2);
        fA[0]=a.x; fA[1]=a.y; fA[2]=a.z; fA[3]=a.w;
        fA[4]=b.x; fA[5]=b.y; fA[6]=b.z; fA[7]=b.w;
        #pragma unroll
        for (int c = 0; c < 8; ++c) fB[c] = fA[c];
    }
    #pragma unroll
    for (int srcl = 0; srcl < 4; ++srcl) {
        #pragma unroll
        for (int c = 0; c < 8; ++c) {
            float hv0 = __shfl(h0[c], srcl, 4);
            float hv1 = __shfl(h1[c], srcl, 4);
            int k = ((c & 4) << 2) + srcl * 4 + (c & 3);
            const float* wr = Wlin + k * OUTC;
            float4 a = *reinterpret_cast<const float4*>(wr + o1);
            float4 b = *reinterpret_cast<const float4*>(wr + o2);
            fA[0]=fmaf(hv0,a.x,fA[0]); fA[1]=fmaf(hv0,a.y,fA[1]);
            fA[2]=fmaf(hv0,a.z,fA[2]); fA[3]=fmaf(hv0,a.w,fA[3]);
            fA[4]=fmaf(hv0,b.x,fA[4]); fA[5]=fmaf(hv0,b.y,fA[5]);
            fA[6]=fmaf(hv0,b.z,fA[6]); fA[7]=fmaf(hv0,b.w,fA[7]);
            fB[0]=fmaf(hv1,a.x,fB[0]); fB[1]=fmaf(hv1,a.y,fB[1]);
            fB[2]=fmaf(hv1,a.z,fB[2]); fB[3]=fmaf(hv1,a.w,fB[3]);
            fB[4]=fmaf(hv1,b.x,fB[4]); fB[5]=fmaf(hv1,b.y,fB[5]);
            fB[6]=fmaf(hv1,b.z,fB[6]); fB[7]=fmaf(hv1,b.w,fB[7]);
        }
    }

    // expand slices -> full f[32] per node via quad shuffles (compile-time)
    float f0[OUTC], f1[OUTC];
    #pragma unroll
    for (int srcl = 0; srcl < 4; ++srcl) {
        #pragma unroll
        for (int c = 0; c < 8; ++c) {
            int k = ((c & 4) << 2) + srcl * 4 + (c & 3);
            f0[k] = __shfl(fA[c], srcl, 4);
            f1[k] = __shfl(fB[c], srcl, 4);
        }
    }

    // ===== Phase B: q_head (pair-reuse of LDS Wq1) =====
    float acc0[32], acc1[32];
    {
        const float4* b4 = reinterpret_cast<const float4*>(bq1 + l * 32);
        #pragma unroll
        for (int j4 = 0; j4 < 8; ++j4) {
            float4 b = b4[j4];
            acc0[j4*4+0]=b.x; acc0[j4*4+1]=b.y; acc0[j4*4+2]=b.z; acc0[j4*4+3]=b.w;
            acc1[j4*4+0]=b.x; acc1[j4*4+1]=b.y; acc1[j4*4+2]=b.z; acc1[j4*4+3]=b.w;
        }
    }
    const float* w1 = sw1 + l * 1032;
    #pragma unroll
    for (int k = 0; k < 32; ++k) {
        float fk0 = f0[k], fk1 = f1[k];
        const float* wr = w1 + k * 32;
        #pragma unroll
        for (int j = 0; j < 32; ++j) {
            float wj = wr[j];
            acc0[j] = fmaf(fk0, wj, acc0[j]);
            acc1[j] = fmaf(fk1, wj, acc1[j]);
        }
    }
    #pragma unroll
    for (int j = 0; j < 32; ++j) {
        acc0[j] = fmaxf(acc0[j], 0.f);
        acc1[j] = fmaxf(acc1[j], 0.f);
    }

    float q0[8], q1[8];
    {
        const float4* b4 = reinterpret_cast<const float4*>(bq2 + l * 8);
        float4 a = b4[0], b = b4[1];
        q0[0]=a.x; q0[1]=a.y; q0[2]=a.z; q0[3]=a.w;
        q0[4]=b.x; q0[5]=b.y; q0[6]=b.z; q0[7]=b.w;
        #pragma unroll
        for (int c = 0; c < 8; ++c) q1[c] = q0[c];
    }
    #pragma unroll
    for (int srcl = 0; srcl < 4; ++srcl) {
        #pragma unroll
        for (int j = 0; j < 32; ++j) {
            float a0 = __shfl(acc0[j], srcl, 4);
            float a1 = __shfl(acc1[j], srcl, 4);
            int m = srcl * 32 + j;
            const float4* w2 = reinterpret_cast<const float4*>(Wq2 + m * NACT + l * 8);
            float4 wa = w2[0], wb = w2[1];
            q0[0]=fmaf(a0,wa.x,q0[0]); q0[1]=fmaf(a0,wa.y,q0[1]);
            q0[2]=fmaf(a0,wa.z,q0[2]); q0[3]=fmaf(a0,wa.w,q0[3]);
            q0[4]=fmaf(a0,wb.x,q0[4]); q0[5]=fmaf(a0,wb.y,q0[5]);
            q0[6]=fmaf(a0,wb.z,q0[6]); q0[7]=fmaf(a0,wb.w,q0[7]);
            q1[0]=fmaf(a1,wa.x,q1[0]); q1[1]=fmaf(a1,wa.y,q1[1]);
            q1[2]=fmaf(a1,wa.z,q1[2]); q1[3]=fmaf(a1,wa.w,q1[3]);
            q1[4]=fmaf(a1,wb.x,q1[4]); q1[5]=fmaf(a1,wb.y,q1[5]);
            q1[6]=fmaf(a1,wb.z,q1[6]); q1[7]=fmaf(a1,wb.w,q1[7]);
        }
    }

    float4* o;
    o = reinterpret_cast<float4*>(out + (size_t)n0 * NACT + l * 8);
    o[0] = make_float4(q0[0], q0[1], q0[2], q0[3]);
    o[1] = make_float4(q0[4], q0[5], q0[6], q0[7]);
    o = reinterpret_cast<float4*>(out + (size_t)n1 * NACT + l * 8);
    o[0] = make_float4(q1[0], q1[1], q1[2], q1[3]);
    o[1] = make_float4(q1[4], q1[5], q1[6], q1[7]);
}

extern "C" void kernel_launch(void* const* d_in, const int* in_sizes, int n_in,
                              void* d_out, int out_size, void* d_ws, size_t ws_size,
                              hipStream_t stream) {
    const float* x     = (const float*)d_in[0];
    const int*   esrc  = (const int*)d_in[1];
    const int*   edst  = (const int*)d_in[2];
    const float* ea    = (const float*)d_in[3];
    const float* We    = (const float*)d_in[4];
    const float* be    = (const float*)d_in[5];
    const float* Wroot = (const float*)d_in[6];
    const float* bconv = (const float*)d_in[7];
    const float* gamma = (const float*)d_in[8];
    const float* beta  = (const float*)d_in[9];
    const float* Wlin  = (const float*)d_in[10];
    const float* blin  = (const float*)d_in[11];
    const float* Wq1   = (const float*)d_in[12];
    const float* bq1   = (const float*)d_in[13];
    const float* Wq2   = (const float*)d_in[14];
    const float* bq2   = (const float*)d_in[15];
    float* out = (float*)d_out;

    // workspace layout (bytes)
    char* ws = (char*)d_ws;
    int*   deg        = (int*)(ws + 0);          // 200704
    int*   slot       = (int*)(ws + 200704);     // 800768
    int*   row_off    = (int*)(ws + 1001472);    // 201728
    int*   partials   = (int*)(ws + 1203200);    // 1024
    float* sorted_msg = (float*)(ws + 1204224);  // 25.6 MB

    hipMemsetAsync(deg, 0, 200704, stream);

    hist_slot_kernel<<<(NE + 255) / 256, 256, 0, stream>>>(edst, deg, slot);
    partial_kernel<<<NPART, 256, 0, stream>>>(deg, partials);
    rowoff2_kernel<<<NPART, 256, 0, stream>>>(deg, partials, row_off);
    edge_q1_kernel<<<(NE * 4 + 255) / 256, 256, 0, stream>>>(
        x, esrc, edst, ea, We, be, row_off, slot, sorted_msg);
    node_fused_kernel<<<(NN / 2 * 4 + 63) / 64, 64, 0, stream>>>(
        x, sorted_msg, row_off, Wroot, bconv, gamma, beta,
        Wlin, blin, Wq1, bq1, Wq2, bq2, out);
}

// Round 23
// 103.534 us; speedup vs baseline: 1.0332x; 1.0332x over previous
//
#include <hip/hip_runtime.h>

#define NN   50000
#define NE   200000
#define INC  16
#define HIDC 32
#define EDGED 8
#define OUTC 32
#define MLPH 128
#define NACT 32

#define NPART 196   // ceil(NN / 256)
#define NQUAD (NE / 2)   // 100000 edge pairs
#define EDGE_GRID 784

typedef float floatx4 __attribute__((ext_vector_type(4)));

// ---- hist + slot in one pass: the atomic counter IS the histogram ----
__global__ __launch_bounds__(256) void hist_slot_kernel(const int* __restrict__ edst,
                                                        int* __restrict__ deg,
                                                        int* __restrict__ slot) {
    int e = blockIdx.x * blockDim.x + threadIdx.x;
    if (e < NE) slot[e] = atomicAdd(&deg[edst[e]], 1);
}

// ---- scan pass 1: per-block sums ----
__global__ __launch_bounds__(256) void partial_kernel(const int* __restrict__ deg,
                                                      int* __restrict__ partials) {
    __shared__ int sm[256];
    int t = threadIdx.x, i = blockIdx.x * 256 + t;
    sm[t] = (i < NN) ? deg[i] : 0;
    __syncthreads();
    #pragma unroll
    for (int off = 128; off > 0; off >>= 1) {
        if (t < off) sm[t] += sm[t + off];
        __syncthreads();
    }
    if (t == 0) partials[blockIdx.x] = sm[0];
}

// ---- scan pass 2 (merged): every block prefixes the 196 partials itself,
//      then block-local scan -> row_off ----
__global__ __launch_bounds__(256) void rowoff2_kernel(const int* __restrict__ deg,
                                                      const int* __restrict__ partials,
                                                      int* __restrict__ row_off) {
    __shared__ int sp[NPART];
    __shared__ int sm[256];
    int t = threadIdx.x, bid = blockIdx.x;
    if (t < NPART) sp[t] = partials[t];
    __syncthreads();
    int base = 0;
    for (int i = 0; i < bid; ++i) base += sp[i];   // uniform, scalar-unit cheap

    int i = bid * 256 + t;
    int d = (i < NN) ? deg[i] : 0;
    sm[t] = d;
    __syncthreads();
    for (int off = 1; off < 256; off <<= 1) {
        int v = (t >= off) ? sm[t - off] : 0;
        __syncthreads();
        sm[t] += v;
        __syncthreads();
    }
    int excl = sm[t] - d + base;
    if (i < NN) {
        row_off[i] = excl;
        if (i == NN - 1) row_off[NN] = excl + d;   // == NE
    }
}

// ---- edge kernel: quad per edge-PAIR, 2 edges/thread, ROLLED i4 loop
//      (proven shape: VGPR 64, zero spill, 47 us — session floor for this
//      decomposition; 1-edge/thread variant measured 52 us). GRID-STRIDED.
//      Lane l owns channels {4l..4l+3, 16+4l..16+4l+3}; quad covers
//      complete 64-B sectors; non-temporal dst-sorted stores. ----
__global__ __launch_bounds__(256, 4) void edge_q2_kernel(
    const float* __restrict__ x,
    const int*   __restrict__ esrc,
    const int*   __restrict__ edst,
    const float* __restrict__ ea,
    const float* __restrict__ We,        // [8][512] original layout
    const float* __restrict__ be,        // [512]
    const int*   __restrict__ row_off,   // [NN+1]
    const int*   __restrict__ slot,      // [NE]
    float*       __restrict__ sorted_msg) // [NE][32] dst-sorted rows
{
    __shared__ float sWe2[4 * 1032];  // [l][(i*8+cc)*8 + d]
    __shared__ float sbe2[4 * 132];   // [l][i*8+cc]
    int t = threadIdx.x;
    for (int idx = t; idx < 4 * 1032; idx += 256) {
        int l = idx / 1032, r = idx - l * 1032;
        float v = 0.f;
        if (r < 1024) {
            int d = r & 7, icc = r >> 3;
            int i = icc >> 3, cc = icc & 7;
            int h = ((cc & 4) << 2) + l * 4 + (cc & 3);   // channel
            v = We[d * 512 + i * 32 + h];
        }
        sWe2[idx] = v;
    }
    for (int idx = t; idx < 4 * 132; idx += 256) {
        int l = idx / 132, r = idx - l * 132;
        float v = 0.f;
        if (r < 128) {
            int i = r >> 3, cc = r & 7;
            int h = ((cc & 4) << 2) + l * 4 + (cc & 3);
            v = be[i * 32 + h];
        }
        sbe2[idx] = v;
    }
    __syncthreads();

    int l = t & 3;
    const float* wl = sWe2 + l * 1032;
    const float* bl = sbe2 + l * 132;

    for (int q = blockIdx.x * 64 + (t >> 2); q < NQUAD; q += EDGE_GRID * 64) {
        int e0 = q, e1 = q + 100000;
        int s0 = esrc[e0], s1 = esrc[e1];
        int p0 = row_off[edst[e0]] + slot[e0];
        int p1 = row_off[edst[e1]] + slot[e1];

        float ea0[8], ea1[8];
        {
            const float4* p;
            float4 a, b;
            p = reinterpret_cast<const float4*>(ea) + (size_t)e0 * 2; a = p[0]; b = p[1];
            ea0[0]=a.x; ea0[1]=a.y; ea0[2]=a.z; ea0[3]=a.w; ea0[4]=b.x; ea0[5]=b.y; ea0[6]=b.z; ea0[7]=b.w;
            p = reinterpret_cast<const float4*>(ea) + (size_t)e1 * 2; a = p[0]; b = p[1];
            ea1[0]=a.x; ea1[1]=a.y; ea1[2]=a.z; ea1[3]=a.w; ea1[4]=b.x; ea1[5]=b.y; ea1[6]=b.z; ea1[7]=b.w;
        }

        float m0[8], m1[8];
        #pragma unroll
        for (int c = 0; c < 8; ++c) { m0[c]=0.f; m1[c]=0.f; }

        const float4* xp0 = reinterpret_cast<const float4*>(x) + (size_t)s0 * 4;
        const float4* xp1 = reinterpret_cast<const float4*>(x) + (size_t)s1 * 4;

        for (int i4 = 0; i4 < 4; ++i4) {    // rolled: keeps live ranges small
            float4 xv0 = xp0[i4], xv1 = xp1[i4];
            float xs0[4] = {xv0.x, xv0.y, xv0.z, xv0.w};
            float xs1[4] = {xv1.x, xv1.y, xv1.z, xv1.w};
            const float* wb4 = wl + i4 * 256;
            const float* bb4 = bl + i4 * 32;
            #pragma unroll
            for (int ii = 0; ii < 4; ++ii) {
                const float* wbase = wb4 + ii * 64;
                const float* bbase = bb4 + ii * 8;
                float xi0 = xs0[ii], xi1 = xs1[ii];
                #pragma unroll
                for (int cc = 0; cc < 8; ++cc) {
                    const float* wr = wbase + cc * 8;
                    float bv = bbase[cc];
                    float w0 = bv, w1 = bv;
                    #pragma unroll
                    for (int d = 0; d < 8; ++d) {
                        float wd = wr[d];
                        w0 = fmaf(ea0[d], wd, w0);
                        w1 = fmaf(ea1[d], wd, w1);
                    }
                    w0 = fmaxf(w0, 0.f); w1 = fmaxf(w1, 0.f);
                    m0[cc] = fmaf(xi0, w0, m0[cc]);
                    m1[cc] = fmaf(xi1, w1, m1[cc]);
                }
            }
        }

        floatx4* o;
        floatx4 v;
        o = reinterpret_cast<floatx4*>(sorted_msg + (size_t)p0 * 32 + l * 4);
        v = (floatx4){m0[0], m0[1], m0[2], m0[3]}; __builtin_nontemporal_store(v, o);
        v = (floatx4){m0[4], m0[5], m0[6], m0[7]}; __builtin_nontemporal_store(v, o + 4);
        o = reinterpret_cast<floatx4*>(sorted_msg + (size_t)p1 * 32 + l * 4);
        v = (floatx4){m1[0], m1[1], m1[2], m1[3]}; __builtin_nontemporal_store(v, o);
        v = (floatx4){m1[4], m1[5], m1[6], m1[7]}; __builtin_nontemporal_store(v, o + 4);
    }
}

// ---- fused node kernel: quad per NODE PAIR (2 nodes/thread), 64-thread
//      blocks (1563 one-wave blocks, fine CU balance), (64,1) full
//      register budget — R21-proven. ----
__global__ __launch_bounds__(64, 1) void node_fused_kernel(
    const float* __restrict__ x,
    const float* __restrict__ sorted_msg,  // [NE][32] dst-sorted
    const int*   __restrict__ row_off,
    const float* __restrict__ Wroot,   // [16][32]
    const float* __restrict__ bconv,
    const float* __restrict__ gamma,
    const float* __restrict__ beta,
    const float* __restrict__ Wlin,    // [32][32]
    const float* __restrict__ blin,
    const float* __restrict__ Wq1,     // [32][128]
    const float* __restrict__ bq1,
    const float* __restrict__ Wq2,     // [128][32]
    const float* __restrict__ bq2,
    float* __restrict__ out)
{
    __shared__ float sw1[4 * 1032];    // [l][k*32+j], stagger 1032
    int t = threadIdx.x;
    for (int w = t; w < 4096; w += 64) {
        int k = w >> 7, m = w & 127, l = m >> 5, j = m & 31;
        sw1[l * 1032 + k * 32 + j] = Wq1[w];
    }
    __syncthreads();

    int gid = blockIdx.x * 64 + t;
    int p = gid >> 2;                  // node pair
    int l = gid & 3;
    if (p >= NN / 2) return;
    int n0 = p * 2, n1 = p * 2 + 1;
    int o1 = l * 4;        // first channel-slice float offset
    int o2 = 16 + l * 4;   // second

    // ===== Phase A: feat for both nodes =====
    float h0[8], h1[8];
    {
        float4 a = *reinterpret_cast<const float4*>(bconv + o1);
        float4 b = *reinterpret_cast<const float4*>(bconv + o2);
        h0[0]=a.x; h0[1]=a.y; h0[2]=a.z; h0[3]=a.w;
        h0[4]=b.x; h0[5]=b.y; h0[6]=b.z; h0[7]=b.w;
        #pragma unroll
        for (int c = 0; c < 8; ++c) h1[c] = h0[c];
    }

    int r0 = row_off[n0], r1 = row_off[n1], r2 = row_off[n1 + 1];
    for (int k = r0; k < r1; ++k) {
        const float* row = sorted_msg + (size_t)k * 32;
        float4 a = *reinterpret_cast<const float4*>(row + o1);
        float4 b = *reinterpret_cast<const float4*>(row + o2);
        h0[0]+=a.x; h0[1]+=a.y; h0[2]+=a.z; h0[3]+=a.w;
        h0[4]+=b.x; h0[5]+=b.y; h0[6]+=b.z; h0[7]+=b.w;
    }
    for (int k = r1; k < r2; ++k) {
        const float* row = sorted_msg + (size_t)k * 32;
        float4 a = *reinterpret_cast<const float4*>(row + o1);
        float4 b = *reinterpret_cast<const float4*>(row + o2);
        h1[0]+=a.x; h1[1]+=a.y; h1[2]+=a.z; h1[3]+=a.w;
        h1[4]+=b.x; h1[5]+=b.y; h1[6]+=b.z; h1[7]+=b.w;
    }

    {
        const float4* xa = reinterpret_cast<const float4*>(x) + (size_t)n0 * 4;
        const float4* xb = reinterpret_cast<const float4*>(x) + (size_t)n1 * 4;
        #pragma unroll
        for (int i4 = 0; i4 < 4; ++i4) {
            float4 xv0 = xa[i4], xv1 = xb[i4];
            float xs0[4] = {xv0.x, xv0.y, xv0.z, xv0.w};
            float xs1[4] = {xv1.x, xv1.y, xv1.z, xv1.w};
            #pragma unroll
            for (int ii = 0; ii < 4; ++ii) {
                const float* wr = Wroot + (i4 * 4 + ii) * HIDC;
                float4 a = *reinterpret_cast<const float4*>(wr + o1);
                float4 b = *reinterpret_cast<const float4*>(wr + o2);
                float xi0 = xs0[ii], xi1 = xs1[ii];
                h0[0]=fmaf(xi0,a.x,h0[0]); h0[1]=fmaf(xi0,a.y,h0[1]);
                h0[2]=fmaf(xi0,a.z,h0[2]); h0[3]=fmaf(xi0,a.w,h0[3]);
                h0[4]=fmaf(xi0,b.x,h0[4]); h0[5]=fmaf(xi0,b.y,h0[5]);
                h0[6]=fmaf(xi0,b.z,h0[6]); h0[7]=fmaf(xi0,b.w,h0[7]);
                h1[0]=fmaf(xi1,a.x,h1[0]); h1[1]=fmaf(xi1,a.y,h1[1]);
                h1[2]=fmaf(xi1,a.z,h1[2]); h1[3]=fmaf(xi1,a.w,h1[3]);
                h1[4]=fmaf(xi1,b.x,h1[4]); h1[5]=fmaf(xi1,b.y,h1[5]);
                h1[6]=fmaf(xi1,b.z,h1[6]); h1[7]=fmaf(xi1,b.w,h1[7]);
            }
        }
    }

    // LayerNorm both nodes (quad butterfly on scalars) + ReLU
    float s0 = ((h0[0]+h0[1])+(h0[2]+h0[3])) + ((h0[4]+h0[5])+(h0[6]+h0[7]));
    float s1 = ((h1[0]+h1[1])+(h1[2]+h1[3])) + ((h1[4]+h1[5])+(h1[6]+h1[7]));
    s0 += __shfl_xor(s0, 1); s0 += __shfl_xor(s0, 2);
    s1 += __shfl_xor(s1, 1); s1 += __shfl_xor(s1, 2);
    float mu0 = s0 * (1.f / HIDC), mu1 = s1 * (1.f / HIDC);
    float v0 = 0.f, v1 = 0.f;
    #pragma unroll
    for (int c = 0; c < 8; ++c) {
        float d0 = h0[c] - mu0; v0 = fmaf(d0, d0, v0);
        float d1 = h1[c] - mu1; v1 = fmaf(d1, d1, v1);
    }
    v0 += __shfl_xor(v0, 1); v0 += __shfl_xor(v0, 2);
    v1 += __shfl_xor(v1, 1); v1 += __shfl_xor(v1, 2);
    float rs0 = rsqrtf(v0 * (1.f / HIDC) + 1e-5f);
    float rs1 = rsqrtf(v1 * (1.f / HIDC) + 1e-5f);
    {
        float4 g0 = *reinterpret_cast<const float4*>(gamma + o1);
        float4 g1 = *reinterpret_cast<const float4*>(gamma + o2);
        float4 b0 = *reinterpret_cast<const float4*>(beta + o1);
        float4 b1 = *reinterpret_cast<const float4*>(beta + o2);
        float gs[8] = {g0.x,g0.y,g0.z,g0.w,g1.x,g1.y,g1.z,g1.w};
        float bs[8] = {b0.x,b0.y,b0.z,b0.w,b1.x,b1.y,b1.z,b1.w};
        #pragma unroll
        for (int c = 0; c < 8; ++c) {
            h0[c] = fmaxf(fmaf((h0[c] - mu0) * rs0, gs[c], bs[c]), 0.f);
            h1[c] = fmaxf(fmaf((h1[c] - mu1) * rs1, gs[c], bs[c]), 0.f);
        }
    }

    // feat slices (complete sums per lane)
    float fA[8], fB[8];
    {
        float4 a = *reinterpret_cast<const float4*>(blin + o1);
        float4 b = *reinterpret_cast<const float4*>(blin + o2);
        fA[0]=a.x; fA[1]=a.y; fA[2]=a.z; fA[3]=a.w;
        fA[4]=b.x; fA[5]=b.y; fA[6]=b.z; fA[7]=b.w;
        #pragma unroll
        for (int c = 0; c < 8; ++c) fB[c] = fA[c];
    }
    #pragma unroll
    for (int srcl = 0; srcl < 4; ++srcl) {
        #pragma unroll
        for (int c = 0; c < 8; ++c) {
            float hv0 = __shfl(h0[c], srcl, 4);
            float hv1 = __shfl(h1[c], srcl, 4);
            int k = ((c & 4) << 2) + srcl * 4 + (c & 3);
            const float* wr = Wlin + k * OUTC;
            float4 a = *reinterpret_cast<const float4*>(wr + o1);
            float4 b = *reinterpret_cast<const float4*>(wr + o2);
            fA[0]=fmaf(hv0,a.x,fA[0]); fA[1]=fmaf(hv0,a.y,fA[1]);
            fA[2]=fmaf(hv0,a.z,fA[2]); fA[3]=fmaf(hv0,a.w,fA[3]);
            fA[4]=fmaf(hv0,b.x,fA[4]); fA[5]=fmaf(hv0,b.y,fA[5]);
            fA[6]=fmaf(hv0,b.z,fA[6]); fA[7]=fmaf(hv0,b.w,fA[7]);
            fB[0]=fmaf(hv1,a.x,fB[0]); fB[1]=fmaf(hv1,a.y,fB[1]);
            fB[2]=fmaf(hv1,a.z,fB[2]); fB[3]=fmaf(hv1,a.w,fB[3]);
            fB[4]=fmaf(hv1,b.x,fB[4]); fB[5]=fmaf(hv1,b.y,fB[5]);
            fB[6]=fmaf(hv1,b.z,fB[6]); fB[7]=fmaf(hv1,b.w,fB[7]);
        }
    }

    // expand slices -> full f[32] per node via quad shuffles (compile-time)
    float f0[OUTC], f1[OUTC];
    #pragma unroll
    for (int srcl = 0; srcl < 4; ++srcl) {
        #pragma unroll
        for (int c = 0; c < 8; ++c) {
            int k = ((c & 4) << 2) + srcl * 4 + (c & 3);
            f0[k] = __shfl(fA[c], srcl, 4);
            f1[k] = __shfl(fB[c], srcl, 4);
        }
    }

    // ===== Phase B: q_head (pair-reuse of LDS Wq1) =====
    float acc0[32], acc1[32];
    {
        const float4* b4 = reinterpret_cast<const float4*>(bq1 + l * 32);
        #pragma unroll
        for (int j4 = 0; j4 < 8; ++j4) {
            float4 b = b4[j4];
            acc0[j4*4+0]=b.x; acc0[j4*4+1]=b.y; acc0[j4*4+2]=b.z; acc0[j4*4+3]=b.w;
            acc1[j4*4+0]=b.x; acc1[j4*4+1]=b.y; acc1[j4*4+2]=b.z; acc1[j4*4+3]=b.w;
        }
    }
    const float* w1 = sw1 + l * 1032;
    #pragma unroll
    for (int k = 0; k < 32; ++k) {
        float fk0 = f0[k], fk1 = f1[k];
        const float* wr = w1 + k * 32;
        #pragma unroll
        for (int j = 0; j < 32; ++j) {
            float wj = wr[j];
            acc0[j] = fmaf(fk0, wj, acc0[j]);
            acc1[j] = fmaf(fk1, wj, acc1[j]);
        }
    }
    #pragma unroll
    for (int j = 0; j < 32; ++j) {
        acc0[j] = fmaxf(acc0[j], 0.f);
        acc1[j] = fmaxf(acc1[j], 0.f);
    }

    float q0[8], q1[8];
    {
        const float4* b4 = reinterpret_cast<const float4*>(bq2 + l * 8);
        float4 a = b4[0], b = b4[1];
        q0[0]=a.x; q0[1]=a.y; q0[2]=a.z; q0[3]=a.w;
        q0[4]=b.x; q0[5]=b.y; q0[6]=b.z; q0[7]=b.w;
        #pragma unroll
        for (int c = 0; c < 8; ++c) q1[c] = q0[c];
    }
    #pragma unroll
    for (int srcl = 0; srcl < 4; ++srcl) {
        #pragma unroll
        for (int j = 0; j < 32; ++j) {
            float a0 = __shfl(acc0[j], srcl, 4);
            float a1 = __shfl(acc1[j], srcl, 4);
            int m = srcl * 32 + j;
            const float4* w2 = reinterpret_cast<const float4*>(Wq2 + m * NACT + l * 8);
            float4 wa = w2[0], wb = w2[1];
            q0[0]=fmaf(a0,wa.x,q0[0]); q0[1]=fmaf(a0,wa.y,q0[1]);
            q0[2]=fmaf(a0,wa.z,q0[2]); q0[3]=fmaf(a0,wa.w,q0[3]);
            q0[4]=fmaf(a0,wb.x,q0[4]); q0[5]=fmaf(a0,wb.y,q0[5]);
            q0[6]=fmaf(a0,wb.z,q0[6]); q0[7]=fmaf(a0,wb.w,q0[7]);
            q1[0]=fmaf(a1,wa.x,q1[0]); q1[1]=fmaf(a1,wa.y,q1[1]);
            q1[2]=fmaf(a1,wa.z,q1[2]); q1[3]=fmaf(a1,wa.w,q1[3]);
            q1[4]=fmaf(a1,wb.x,q1[4]); q1[5]=fmaf(a1,wb.y,q1[5]);
            q1[6]=fmaf(a1,wb.z,q1[6]); q1[7]=fmaf(a1,wb.w,q1[7]);
        }
    }

    float4* o;
    o = reinterpret_cast<float4*>(out + (size_t)n0 * NACT + l * 8);
    o[0] = make_float4(q0[0], q0[1], q0[2], q0[3]);
    o[1] = make_float4(q0[4], q0[5], q0[6], q0[7]);
    o = reinterpret_cast<float4*>(out + (size_t)n1 * NACT + l * 8);
    o[0] = make_float4(q1[0], q1[1], q1[2], q1[3]);
    o[1] = make_float4(q1[4], q1[5], q1[6], q1[7]);
}

extern "C" void kernel_launch(void* const* d_in, const int* in_sizes, int n_in,
                              void* d_out, int out_size, void* d_ws, size_t ws_size,
                              hipStream_t stream) {
    const float* x     = (const float*)d_in[0];
    const int*   esrc  = (const int*)d_in[1];
    const int*   edst  = (const int*)d_in[2];
    const float* ea    = (const float*)d_in[3];
    const float* We    = (const float*)d_in[4];
    const float* be    = (const float*)d_in[5];
    const float* Wroot = (const float*)d_in[6];
    const float* bconv = (const float*)d_in[7];
    const float* gamma = (const float*)d_in[8];
    const float* beta  = (const float*)d_in[9];
    const float* Wlin  = (const float*)d_in[10];
    const float* blin  = (const float*)d_in[11];
    const float* Wq1   = (const float*)d_in[12];
    const float* bq1   = (const float*)d_in[13];
    const float* Wq2   = (const float*)d_in[14];
    const float* bq2   = (const float*)d_in[15];
    float* out = (float*)d_out;

    // workspace layout (bytes)
    char* ws = (char*)d_ws;
    int*   deg        = (int*)(ws + 0);          // 200704
    int*   slot       = (int*)(ws + 200704);     // 800768
    int*   row_off    = (int*)(ws + 1001472);    // 201728
    int*   partials   = (int*)(ws + 1203200);    // 1024
    float* sorted_msg = (float*)(ws + 1204224);  // 25.6 MB

    hipMemsetAsync(deg, 0, 200704, stream);

    hist_slot_kernel<<<(NE + 255) / 256, 256, 0, stream>>>(edst, deg, slot);
    partial_kernel<<<NPART, 256, 0, stream>>>(deg, partials);
    rowoff2_kernel<<<NPART, 256, 0, stream>>>(deg, partials, row_off);
    edge_q2_kernel<<<EDGE_GRID, 256, 0, stream>>>(
        x, esrc, edst, ea, We, be, row_off, slot, sorted_msg);
    node_fused_kernel<<<(NN / 2 * 4 + 63) / 64, 64, 0, stream>>>(
        x, sorted_msg, row_off, Wroot, bconv, gamma, beta,
        Wlin, blin, Wq1, bq1, Wq2, bq2, out);
}